// Round 6
// baseline (272.115 us; speedup 1.0000x reference)
//
#include <hip/hip_runtime.h>
#include <stdint.h>
#include <stddef.h>

// ---------------------------------------------------------------------------
// HHGNN: x = LN(route_by_type(embeds @ W[t] + b[t], mask)) ;
//        lat = adj^T @ x ; ret = adj @ lat
// Shapes: B=8, N=4096, M=2048, H=128, T=13. adj fp32 [B][N][M].
// R6 vs R5 (215.4us): ONE lever — 4 blocks/CU instead of 2.
//  BM 32 -> 16 for both GEMMs: LDS 40 -> 36 KB/block, k2 grid 1024,
//  k3 grid 2048. Rationale: the end-of-step __syncthreads drains the
//  freshly-issued stage_B (HIP barrier = vmcnt(0)); exposed stall =
//  HBM latency - compute. With 2 blocks/CU that gap is uncovered; 4
//  independent barrier groups interleave through each other's stalls.
//  Everything else (BK=64, gload_lds B-staging with pre-swizzled source,
//  granule-XOR LDS layout, cvtpk A-conversion, issue-early/write-late
//  schedule) is unchanged from the R5-validated structure.
// ws: xT 8.39MB + latT 4.19MB.
// ---------------------------------------------------------------------------

typedef float    f32x4_t  __attribute__((ext_vector_type(4)));
typedef __bf16   bf16x8_t __attribute__((ext_vector_type(8)));
typedef unsigned int u32x4_t __attribute__((ext_vector_type(4)));
typedef unsigned int u32x2_t __attribute__((ext_vector_type(2)));

__device__ __forceinline__ unsigned short f2bf(float f) {
    union { float f; unsigned int u; } v; v.f = f;
    unsigned int u = v.u;
    return (unsigned short)((u + 0x7FFFu + ((u >> 16) & 1u)) >> 16);
}

// packed RNE fp32x2 -> bf16x2 (lo=a, hi=b)
__device__ __forceinline__ unsigned int cvtpk(float a, float b) {
    unsigned int r;
    asm("v_cvt_pk_bf16_f32 %0, %1, %2" : "=v"(r) : "v"(a), "v"(b));
    return r;
}

__device__ __forceinline__ bool mask_on(const unsigned char* m, int gid) {
    return (m[gid] | m[(gid >> 2) << 2]) != 0;
}

// byte offset of 16B-granule g in row `row` of a [rows][64] bf16 LDS panel,
// granule-XOR swizzled by (row&7)
__device__ __forceinline__ int foff(int row, int g) {
    return row * 128 + (((g) ^ (row & 7)) << 4);
}

// ---------------------------------------------------------------------------
// B-panel staging: 128 rows x 64 bf16 via global_load_lds, 16B per lane.
// LDS dest linear; bank swizzle realized by pre-swizzled SOURCE granule.
// ---------------------------------------------------------------------------
template<int GSTRIDE>
__device__ __forceinline__ void stage_B(const unsigned short* __restrict__ gb,
                                        int k0, unsigned short* ldsB, int t)
{
    const int l = t & 63, w = t >> 6;
    const int hsub = l >> 3;                       // row within 8-row group
    const int csrc = ((l & 7) ^ hsub) << 3;        // swizzled source k-granule
    #pragma unroll
    for (int i = 0; i < 4; ++i) {
        const int hbase = i * 32 + w * 8;
        const unsigned short* src = gb + (size_t)(hbase + hsub) * GSTRIDE + k0 + csrc;
        unsigned short* dst = ldsB + hbase * 64;   // wave-uniform base
        __builtin_amdgcn_global_load_lds(
            (__attribute__((address_space(1))) void*)src,
            (__attribute__((address_space(3))) void*)dst, 16, 0, 0);
    }
}

// ---------------------------------------------------------------------------
// Kernel 1: per-type linear + bias + mask + LayerNorm -> xT bf16 [B][H][N]
// (unchanged from R1)
// ---------------------------------------------------------------------------
__global__ __launch_bounds__(256) void k1_typed_ln(
    const float* __restrict__ embeds,
    const int*   __restrict__ ntype,
    const unsigned char* __restrict__ mask8,
    const float* __restrict__ W,
    const float* __restrict__ bias,
    const float* __restrict__ gamma,
    const float* __restrict__ beta,
    unsigned short* __restrict__ xT)
{
    __shared__ float e_lds[128][132];
    __shared__ float W_lds[128][128];
    __shared__ float b_lds[13 * 128];
    __shared__ float g_lds[128];
    __shared__ float be_lds[128];
    __shared__ unsigned short lists[13][128];
    __shared__ int cnt[13];

    const int t   = threadIdx.x;
    const int blk = blockIdx.x;
    const int b   = blk >> 5;
    const int n0  = (blk & 31) << 7;
    const float* ebase = embeds + ((size_t)b * 4096 + n0) * 128;

    for (int it = 0; it < 16; ++it) {
        int idx = it * 256 + t;
        int n = idx >> 5, c = idx & 31;
        float4 v = *(const float4*)(ebase + n * 128 + c * 4);
        *(float4*)(&e_lds[n][c * 4]) = v;
    }
    for (int i = t; i < 13 * 128; i += 256) b_lds[i] = bias[i];
    if (t < 128) { g_lds[t] = gamma[t]; be_lds[t] = beta[t]; }
    if (t < 13) cnt[t] = 0;
    __syncthreads();

    if (t < 128) {
        int ty = ntype[(size_t)b * 4096 + n0 + t];
        int slot = atomicAdd(&cnt[ty], 1);
        lists[ty][slot] = (unsigned short)t;
    }
    __syncthreads();

    const int lane = t & 63;
    const int wv   = t >> 6;

    for (int ty = 0; ty < 13; ++ty) {
        const int c = cnt[ty];
        __syncthreads();
        if (c > 0) {
            const float* Wt = W + (size_t)ty * 128 * 128;
            for (int it = 0; it < 16; ++it) {
                int idx = it * 256 + t;
                *(float4*)(&W_lds[idx >> 5][(idx & 31) * 4]) = *(const float4*)(Wt + idx * 4);
            }
        }
        __syncthreads();
        if (c == 0) continue;

        const int ngr = (c + 3) >> 2;
        for (int g = wv; g < ngr; g += 4) {
            int base = g * 4;
            int i1 = min(base + 1, c - 1), i2 = min(base + 2, c - 1), i3 = min(base + 3, c - 1);
            int nA = lists[ty][base], nB = lists[ty][i1], nC = lists[ty][i2], nD = lists[ty][i3];
            float a0 = 0, a1 = 0, a2 = 0, a3 = 0, a4 = 0, a5 = 0, a6 = 0, a7 = 0;
            for (int h = 0; h < 128; h += 4) {
                float4 eA = *(const float4*)(&e_lds[nA][h]);
                float4 eB = *(const float4*)(&e_lds[nB][h]);
                float4 eC = *(const float4*)(&e_lds[nC][h]);
                float4 eD = *(const float4*)(&e_lds[nD][h]);
                float w0 = W_lds[h + 0][lane],      w1 = W_lds[h + 1][lane];
                float w2 = W_lds[h + 2][lane],      w3 = W_lds[h + 3][lane];
                float v0 = W_lds[h + 0][lane + 64], v1 = W_lds[h + 1][lane + 64];
                float v2 = W_lds[h + 2][lane + 64], v3 = W_lds[h + 3][lane + 64];
                a0 += eA.x * w0 + eA.y * w1 + eA.z * w2 + eA.w * w3;
                a1 += eB.x * w0 + eB.y * w1 + eB.z * w2 + eB.w * w3;
                a2 += eC.x * w0 + eC.y * w1 + eC.z * w2 + eC.w * w3;
                a3 += eD.x * w0 + eD.y * w1 + eD.z * w2 + eD.w * w3;
                a4 += eA.x * v0 + eA.y * v1 + eA.z * v2 + eA.w * v3;
                a5 += eB.x * v0 + eB.y * v1 + eB.z * v2 + eB.w * v3;
                a6 += eC.x * v0 + eC.y * v1 + eC.z * v2 + eC.w * v3;
                a7 += eD.x * v0 + eD.y * v1 + eD.z * v2 + eD.w * v3;
            }
            float bl = b_lds[ty * 128 + lane], bh = b_lds[ty * 128 + lane + 64];
            a0 += bl; a1 += bl; a2 += bl; a3 += bl;
            a4 += bh; a5 += bh; a6 += bh; a7 += bh;
            int gbase = b * 4096 + n0;
            if (mask_on(mask8, gbase + nA)) { e_lds[nA][lane] = a0; e_lds[nA][lane + 64] = a4; }
            if (mask_on(mask8, gbase + nB)) { e_lds[nB][lane] = a1; e_lds[nB][lane + 64] = a5; }
            if (mask_on(mask8, gbase + nC)) { e_lds[nC][lane] = a2; e_lds[nC][lane + 64] = a6; }
            if (mask_on(mask8, gbase + nD)) { e_lds[nD][lane] = a3; e_lds[nD][lane + 64] = a7; }
        }
    }
    __syncthreads();

    for (int i = 0; i < 32; ++i) {
        int n = wv + i * 4;
        float2 v = *(const float2*)(&e_lds[n][lane * 2]);
        float s = v.x + v.y;
        float q = v.x * v.x + v.y * v.y;
        #pragma unroll
        for (int mskw = 32; mskw >= 1; mskw >>= 1) {
            s += __shfl_xor(s, mskw);
            q += __shfl_xor(q, mskw);
        }
        float mu  = s * 0.0078125f;
        float var = q * 0.0078125f - mu * mu;
        float r   = rsqrtf(var + 1e-5f);
        float2 o;
        o.x = (v.x - mu) * r * g_lds[lane * 2]     + be_lds[lane * 2];
        o.y = (v.y - mu) * r * g_lds[lane * 2 + 1] + be_lds[lane * 2 + 1];
        *(float2*)(&e_lds[n][lane * 2]) = o;
    }
    __syncthreads();

    const int nl = t & 127;
    const int hg = t >> 7;
    unsigned short* xrow = xT + (size_t)b * 128 * 4096 + n0 + nl;
    for (int i = 0; i < 64; ++i) {
        int h = hg * 64 + i;
        xrow[(size_t)h * 4096] = f2bf(e_lds[nl][h]);
    }
}

// ---------------------------------------------------------------------------
// Kernel 2: latT[b][h][m] = sum_n adj[b][n][m] * x[b][n][h]
// grid 1024 = 8b x 128mt(16m). 4 waves (1m x 4h), BK=64, 64 steps.
// LDS 36KB -> 4 blocks/CU. Step: {LOAD_A(s+1)+stage_B(s+1); MFMA(s);
// WRITE_A(s+1); bar}.
// ---------------------------------------------------------------------------
__global__ __launch_bounds__(256) void k2_lat(
    const float* __restrict__ adj,
    const unsigned short* __restrict__ xT,
    unsigned short* __restrict__ latT)
{
    __shared__ unsigned short Al[2][16 * 64];    // [m][k] bf16
    __shared__ unsigned short Bl[2][128 * 64];   // [h][k] bf16

    const int t   = threadIdx.x;
    const int bid = blockIdx.x;
    const int b   = bid & 7;
    const int m0  = (bid >> 3) << 4;
    const float* adjb = adj + (size_t)b * 4096 * 2048;
    const unsigned short* xb = xT + (size_t)b * 128 * 4096;

    const int lane = t & 63, wv = t >> 6;
    const int wh = wv;                 // wave h-block (32 h's)

    // A staging (t<128): kp = k-pair 0..31, c = m-chunk 0..3 (4 m's)
    const int a_kp = t >> 2;
    const int a_c  = (t & 3) << 2;

    const int fr = lane & 15, fg = lane >> 4;
    int offA[2], offB[2][2];
    #pragma unroll
    for (int kk = 0; kk < 2; ++kk) offA[kk] = foff(fr, kk * 4 + fg);
    #pragma unroll
    for (int j = 0; j < 2; ++j)
        #pragma unroll
        for (int kk = 0; kk < 2; ++kk)
            offB[j][kk] = foff(wh * 32 + j * 16 + fr, kk * 4 + fg);

    f32x4_t ar0, ar1;
    auto LOAD_A = [&](int k0) {
        if (t < 128) {
            const float* p = adjb + (size_t)(k0 + a_kp * 2) * 2048 + m0 + a_c;
            ar0 = *(const f32x4_t*)(p);
            ar1 = *(const f32x4_t*)(p + 2048);
        }
    };
    auto WRITE_A = [&](int buf) {
        if (t < 128) {
            const int g = a_kp >> 2, wrd = a_kp & 3;
            #pragma unroll
            for (int j = 0; j < 4; ++j) {
                const int m = a_c + j;
                unsigned int pk = cvtpk(ar0[j], ar1[j]);
                *(unsigned int*)((char*)(&Al[buf][0]) + m * 128 + ((g ^ (m & 7)) << 4) + wrd * 4) = pk;
            }
        }
    };

    f32x4_t acc[2];
    acc[0] = f32x4_t{0.f, 0.f, 0.f, 0.f};
    acc[1] = f32x4_t{0.f, 0.f, 0.f, 0.f};

    LOAD_A(0);
    stage_B<4096>(xb, 0, &Bl[0][0], t);
    WRITE_A(0);
    __syncthreads();

    for (int s = 0; s < 64; ++s) {
        const int buf = s & 1;
        if (s < 63) {
            LOAD_A((s + 1) * 64);
            stage_B<4096>(xb, (s + 1) * 64, &Bl[buf ^ 1][0], t);
        }
        bf16x8_t af[2];
        #pragma unroll
        for (int kk = 0; kk < 2; ++kk)
            af[kk] = __builtin_bit_cast(bf16x8_t,
                *(const u32x4_t*)((const char*)(&Al[buf][0]) + offA[kk]));
        #pragma unroll
        for (int j = 0; j < 2; ++j) {
            #pragma unroll
            for (int kk = 0; kk < 2; ++kk) {
                bf16x8_t bfj = __builtin_bit_cast(bf16x8_t,
                    *(const u32x4_t*)((const char*)(&Bl[buf][0]) + offB[j][kk]));
                acc[j] = __builtin_amdgcn_mfma_f32_16x16x32_bf16(af[kk], bfj, acc[j], 0, 0, 0);
            }
        }
        if (s < 63) WRITE_A(buf ^ 1);
        __syncthreads();
    }

    const int mrow = m0 + (lane >> 4) * 4;
    #pragma unroll
    for (int j = 0; j < 2; ++j) {
        int col = wh * 32 + j * 16 + fr;
        u32x2_t o;
        o[0] = cvtpk(acc[j][0], acc[j][1]);
        o[1] = cvtpk(acc[j][2], acc[j][3]);
        *(u32x2_t*)(latT + (size_t)(b * 128 + col) * 2048 + mrow) = o;
    }
}

// ---------------------------------------------------------------------------
// Kernel 3: ret[b][n][h] = sum_m adj[b][n][m] * latT[b][h][m]
// grid 2048 = 8b x 256nt(16n). 4 waves (1n x 4h), BK=64, 32 steps.
// A rows k-contiguous: f32x4 -> 2 cvtpk -> b64 granule-XOR write.
// ---------------------------------------------------------------------------
__global__ __launch_bounds__(256) void k3_ret(
    const float* __restrict__ adj,
    const unsigned short* __restrict__ latT,
    float* __restrict__ ret)
{
    __shared__ unsigned short Al[2][16 * 64];    // [n][k] bf16
    __shared__ unsigned short Bl[2][128 * 64];   // [h][k] bf16

    const int t   = threadIdx.x;
    const int bid = blockIdx.x;
    const int b   = bid & 7;
    const int n0  = (bid >> 3) << 4;
    const float* adjb = adj + (size_t)b * 4096 * 2048;
    const unsigned short* lb = latT + (size_t)b * 128 * 2048;

    const int lane = t & 63, wv = t >> 6;
    const int wh = wv;

    const int a_r = t >> 4;         // n-row 0..15
    const int a_c = t & 15;         // f32x4 chunk 0..15 (4 k's)

    const int fr = lane & 15, fg = lane >> 4;
    int offA[2], offB[2][2];
    #pragma unroll
    for (int kk = 0; kk < 2; ++kk) offA[kk] = foff(fr, kk * 4 + fg);
    #pragma unroll
    for (int j = 0; j < 2; ++j)
        #pragma unroll
        for (int kk = 0; kk < 2; ++kk)
            offB[j][kk] = foff(wh * 32 + j * 16 + fr, kk * 4 + fg);

    f32x4_t ar;
    auto LOAD_A = [&](int k0) {
        ar = *(const f32x4_t*)(adjb + (size_t)(n0 + a_r) * 2048 + k0 + a_c * 4);
    };
    auto WRITE_A = [&](int buf) {
        u32x2_t pk;
        pk[0] = cvtpk(ar[0], ar[1]);
        pk[1] = cvtpk(ar[2], ar[3]);
        *(u32x2_t*)((char*)(&Al[buf][0]) + a_r * 128
                    + (((a_c >> 1) ^ (a_r & 7)) << 4) + (a_c & 1) * 8) = pk;
    };

    f32x4_t acc[2];
    acc[0] = f32x4_t{0.f, 0.f, 0.f, 0.f};
    acc[1] = f32x4_t{0.f, 0.f, 0.f, 0.f};

    LOAD_A(0);
    stage_B<2048>(lb, 0, &Bl[0][0], t);
    WRITE_A(0);
    __syncthreads();

    for (int s = 0; s < 32; ++s) {
        const int buf = s & 1;
        if (s < 31) {
            LOAD_A((s + 1) * 64);
            stage_B<2048>(lb, (s + 1) * 64, &Bl[buf ^ 1][0], t);
        }
        bf16x8_t af[2];
        #pragma unroll
        for (int kk = 0; kk < 2; ++kk)
            af[kk] = __builtin_bit_cast(bf16x8_t,
                *(const u32x4_t*)((const char*)(&Al[buf][0]) + offA[kk]));
        #pragma unroll
        for (int j = 0; j < 2; ++j) {
            #pragma unroll
            for (int kk = 0; kk < 2; ++kk) {
                bf16x8_t bfj = __builtin_bit_cast(bf16x8_t,
                    *(const u32x4_t*)((const char*)(&Bl[buf][0]) + offB[j][kk]));
                acc[j] = __builtin_amdgcn_mfma_f32_16x16x32_bf16(af[kk], bfj, acc[j], 0, 0, 0);
            }
        }
        if (s < 31) WRITE_A(buf ^ 1);
        __syncthreads();
    }

    const int nrow = n0 + (lane >> 4) * 4;
    #pragma unroll
    for (int j = 0; j < 2; ++j) {
        int col = wh * 32 + j * 16 + fr;
        #pragma unroll
        for (int jj = 0; jj < 4; ++jj) {
            ret[((size_t)b * 4096 + nrow + jj) * 128 + col] = acc[j][jj];
        }
    }
}

// ---------------------------------------------------------------------------
extern "C" void kernel_launch(void* const* d_in, const int* in_sizes, int n_in,
                              void* d_out, int out_size, void* d_ws, size_t ws_size,
                              hipStream_t stream) {
    const float* adj    = (const float*)d_in[0];
    const float* embeds = (const float*)d_in[1];
    const int*   ntype  = (const int*)d_in[2];
    const unsigned char* mask8 = (const unsigned char*)d_in[3];
    const float* W      = (const float*)d_in[4];
    const float* bias   = (const float*)d_in[5];
    const float* gamma  = (const float*)d_in[6];
    const float* beta   = (const float*)d_in[7];
    float* ret = (float*)d_out;

    unsigned short* xT   = (unsigned short*)d_ws;                   // 8.39 MB
    unsigned short* latT = xT + (size_t)8 * 128 * 4096;             // 4.19 MB
    // ws needed: 12.6 MB

    hipLaunchKernelGGL(k1_typed_ln, dim3(256), dim3(256), 0, stream,
                       embeds, ntype, mask8, W, bias, gamma, beta, xT);
    hipLaunchKernelGGL(k2_lat, dim3(1024), dim3(256), 0, stream, adj, xT, latT);
    hipLaunchKernelGGL(k3_ret, dim3(2048), dim3(256), 0, stream, adj, latT, ret);
}

// Round 7
// 228.418 us; speedup vs baseline: 1.1913x; 1.1913x over previous
//
#include <hip/hip_runtime.h>
#include <stdint.h>
#include <stddef.h>

// ---------------------------------------------------------------------------
// HHGNN: x = LN(route_by_type(embeds @ W[t] + b[t], mask)) ;
//        lat = adj^T @ x ; ret = adj @ lat
// Shapes: B=8, N=4096, M=2048, H=128, T=13. adj fp32 [B][N][M].
// R7 vs R5 (215.4us best; R6 BM16 regressed -> reverted): ONE lever —
// T4 counted-vmcnt pipeline on the R5 structure. Raw s_barrier + manual
// s_waitcnt vmcnt(N); B-panel triple-buffered, A double-buffered, 2 A-reg
// sets, prefetch distance 2. Loads for step s+2 stay in flight ACROSS the
// barrier ending step s (24KB/block); __syncthreads (which drains vmcnt(0))
// is eliminated from the k-loop entirely.
// Wave-symmetric wait audit (per wave, 6 VMEM/step: 2 A + 4 B):
//   step s: issue A(s+2),B(s+2) [out 12] -> compute(s) -> vmcnt(10)=A(s+1)
//   done -> ds_write A(s+1) -> vmcnt(6)=B(s+1) done -> lgkmcnt(0) ->
//   s_barrier.  Entering s+1: A/B(s+1) complete for ALL waves.
//   Stage target (s+2)%3 == (s-1)%3: its readers finished at barrier(s-1).
// ws: xT 8.39MB + latT 4.19MB.
// ---------------------------------------------------------------------------

typedef float    f32x4_t  __attribute__((ext_vector_type(4)));
typedef __bf16   bf16x8_t __attribute__((ext_vector_type(8)));
typedef unsigned int u32x4_t __attribute__((ext_vector_type(4)));
typedef unsigned int u32x2_t __attribute__((ext_vector_type(2)));

#define VMCNT(n)  asm volatile("s_waitcnt vmcnt(" #n ")" ::: "memory")
#define LGKM0()   asm volatile("s_waitcnt lgkmcnt(0)" ::: "memory")
#define BARRIER() do { __builtin_amdgcn_s_barrier(); \
                       __builtin_amdgcn_sched_barrier(0); } while (0)

__device__ __forceinline__ unsigned short f2bf(float f) {
    union { float f; unsigned int u; } v; v.f = f;
    unsigned int u = v.u;
    return (unsigned short)((u + 0x7FFFu + ((u >> 16) & 1u)) >> 16);
}

// packed RNE fp32x2 -> bf16x2 (lo=a, hi=b)
__device__ __forceinline__ unsigned int cvtpk(float a, float b) {
    unsigned int r;
    asm("v_cvt_pk_bf16_f32 %0, %1, %2" : "=v"(r) : "v"(a), "v"(b));
    return r;
}

__device__ __forceinline__ bool mask_on(const unsigned char* m, int gid) {
    return (m[gid] | m[(gid >> 2) << 2]) != 0;
}

// byte offset of logical 16B-granule g in row `row` of a [rows][64] bf16
// LDS panel, granule-XOR swizzled by (row&7)
__device__ __forceinline__ int foff(int row, int g) {
    return row * 128 + (((g) ^ (row & 7)) << 4);
}

// B-panel staging: 128 rows x 64 bf16 via global_load_lds, 16B/lane; LDS
// linear, swizzle realized by pre-swizzled SOURCE granule (m173 pattern).
template<int GSTRIDE>
__device__ __forceinline__ void stage_B(const unsigned short* __restrict__ gb,
                                        int k0, unsigned short* ldsB, int t)
{
    const int l = t & 63, w = t >> 6;
    const int hsub = l >> 3;
    const int csrc = ((l & 7) ^ hsub) << 3;
    #pragma unroll
    for (int i = 0; i < 4; ++i) {
        const int hbase = i * 32 + w * 8;
        const unsigned short* src = gb + (size_t)(hbase + hsub) * GSTRIDE + k0 + csrc;
        unsigned short* dst = ldsB + hbase * 64;
        __builtin_amdgcn_global_load_lds(
            (__attribute__((address_space(1))) void*)src,
            (__attribute__((address_space(3))) void*)dst, 16, 0, 0);
    }
}

// ---------------------------------------------------------------------------
// Kernel 1: per-type linear + bias + mask + LayerNorm -> xT bf16 [B][H][N]
// (unchanged from R1)
// ---------------------------------------------------------------------------
__global__ __launch_bounds__(256) void k1_typed_ln(
    const float* __restrict__ embeds,
    const int*   __restrict__ ntype,
    const unsigned char* __restrict__ mask8,
    const float* __restrict__ W,
    const float* __restrict__ bias,
    const float* __restrict__ gamma,
    const float* __restrict__ beta,
    unsigned short* __restrict__ xT)
{
    __shared__ float e_lds[128][132];
    __shared__ float W_lds[128][128];
    __shared__ float b_lds[13 * 128];
    __shared__ float g_lds[128];
    __shared__ float be_lds[128];
    __shared__ unsigned short lists[13][128];
    __shared__ int cnt[13];

    const int t   = threadIdx.x;
    const int blk = blockIdx.x;
    const int b   = blk >> 5;
    const int n0  = (blk & 31) << 7;
    const float* ebase = embeds + ((size_t)b * 4096 + n0) * 128;

    for (int it = 0; it < 16; ++it) {
        int idx = it * 256 + t;
        int n = idx >> 5, c = idx & 31;
        float4 v = *(const float4*)(ebase + n * 128 + c * 4);
        *(float4*)(&e_lds[n][c * 4]) = v;
    }
    for (int i = t; i < 13 * 128; i += 256) b_lds[i] = bias[i];
    if (t < 128) { g_lds[t] = gamma[t]; be_lds[t] = beta[t]; }
    if (t < 13) cnt[t] = 0;
    __syncthreads();

    if (t < 128) {
        int ty = ntype[(size_t)b * 4096 + n0 + t];
        int slot = atomicAdd(&cnt[ty], 1);
        lists[ty][slot] = (unsigned short)t;
    }
    __syncthreads();

    const int lane = t & 63;
    const int wv   = t >> 6;

    for (int ty = 0; ty < 13; ++ty) {
        const int c = cnt[ty];
        __syncthreads();
        if (c > 0) {
            const float* Wt = W + (size_t)ty * 128 * 128;
            for (int it = 0; it < 16; ++it) {
                int idx = it * 256 + t;
                *(float4*)(&W_lds[idx >> 5][(idx & 31) * 4]) = *(const float4*)(Wt + idx * 4);
            }
        }
        __syncthreads();
        if (c == 0) continue;

        const int ngr = (c + 3) >> 2;
        for (int g = wv; g < ngr; g += 4) {
            int base = g * 4;
            int i1 = min(base + 1, c - 1), i2 = min(base + 2, c - 1), i3 = min(base + 3, c - 1);
            int nA = lists[ty][base], nB = lists[ty][i1], nC = lists[ty][i2], nD = lists[ty][i3];
            float a0 = 0, a1 = 0, a2 = 0, a3 = 0, a4 = 0, a5 = 0, a6 = 0, a7 = 0;
            for (int h = 0; h < 128; h += 4) {
                float4 eA = *(const float4*)(&e_lds[nA][h]);
                float4 eB = *(const float4*)(&e_lds[nB][h]);
                float4 eC = *(const float4*)(&e_lds[nC][h]);
                float4 eD = *(const float4*)(&e_lds[nD][h]);
                float w0 = W_lds[h + 0][lane],      w1 = W_lds[h + 1][lane];
                float w2 = W_lds[h + 2][lane],      w3 = W_lds[h + 3][lane];
                float v0 = W_lds[h + 0][lane + 64], v1 = W_lds[h + 1][lane + 64];
                float v2 = W_lds[h + 2][lane + 64], v3 = W_lds[h + 3][lane + 64];
                a0 += eA.x * w0 + eA.y * w1 + eA.z * w2 + eA.w * w3;
                a1 += eB.x * w0 + eB.y * w1 + eB.z * w2 + eB.w * w3;
                a2 += eC.x * w0 + eC.y * w1 + eC.z * w2 + eC.w * w3;
                a3 += eD.x * w0 + eD.y * w1 + eD.z * w2 + eD.w * w3;
                a4 += eA.x * v0 + eA.y * v1 + eA.z * v2 + eA.w * v3;
                a5 += eB.x * v0 + eB.y * v1 + eB.z * v2 + eB.w * v3;
                a6 += eC.x * v0 + eC.y * v1 + eC.z * v2 + eC.w * v3;
                a7 += eD.x * v0 + eD.y * v1 + eD.z * v2 + eD.w * v3;
            }
            float bl = b_lds[ty * 128 + lane], bh = b_lds[ty * 128 + lane + 64];
            a0 += bl; a1 += bl; a2 += bl; a3 += bl;
            a4 += bh; a5 += bh; a6 += bh; a7 += bh;
            int gbase = b * 4096 + n0;
            if (mask_on(mask8, gbase + nA)) { e_lds[nA][lane] = a0; e_lds[nA][lane + 64] = a4; }
            if (mask_on(mask8, gbase + nB)) { e_lds[nB][lane] = a1; e_lds[nB][lane + 64] = a5; }
            if (mask_on(mask8, gbase + nC)) { e_lds[nC][lane] = a2; e_lds[nC][lane + 64] = a6; }
            if (mask_on(mask8, gbase + nD)) { e_lds[nD][lane] = a3; e_lds[nD][lane + 64] = a7; }
        }
    }
    __syncthreads();

    for (int i = 0; i < 32; ++i) {
        int n = wv + i * 4;
        float2 v = *(const float2*)(&e_lds[n][lane * 2]);
        float s = v.x + v.y;
        float q = v.x * v.x + v.y * v.y;
        #pragma unroll
        for (int mskw = 32; mskw >= 1; mskw >>= 1) {
            s += __shfl_xor(s, mskw);
            q += __shfl_xor(q, mskw);
        }
        float mu  = s * 0.0078125f;
        float var = q * 0.0078125f - mu * mu;
        float r   = rsqrtf(var + 1e-5f);
        float2 o;
        o.x = (v.x - mu) * r * g_lds[lane * 2]     + be_lds[lane * 2];
        o.y = (v.y - mu) * r * g_lds[lane * 2 + 1] + be_lds[lane * 2 + 1];
        *(float2*)(&e_lds[n][lane * 2]) = o;
    }
    __syncthreads();

    const int nl = t & 127;
    const int hg = t >> 7;
    unsigned short* xrow = xT + (size_t)b * 128 * 4096 + n0 + nl;
    for (int i = 0; i < 64; ++i) {
        int h = hg * 64 + i;
        xrow[(size_t)h * 4096] = f2bf(e_lds[nl][h]);
    }
}

// ---------------------------------------------------------------------------
// Kernel 2: latT[b][h][m] = sum_n adj[b][n][m] * x[b][n][h]
// grid 512 = 8b x 64mt(32m). 4 waves (2m x 2h), BK=64, NS=64 steps.
// Counted-vmcnt pipeline, prefetch distance 2. LDS 56KB -> 2 blocks/CU.
// ---------------------------------------------------------------------------
__global__ __launch_bounds__(256) void k2_lat(
    const float* __restrict__ adj,
    const unsigned short* __restrict__ xT,
    unsigned short* __restrict__ latT)
{
    __shared__ unsigned short Al[2][32 * 64];    // [m][k] bf16, dbuf
    __shared__ unsigned short Bl[3][128 * 64];   // [h][k] bf16, 3-buf

    const int t   = threadIdx.x;
    const int bid = blockIdx.x;
    const int b   = bid & 7;
    const int m0  = (bid >> 3) << 5;
    const float* adjb = adj + (size_t)b * 4096 * 2048;
    const unsigned short* xb = xT + (size_t)b * 128 * 4096;

    const int lane = t & 63, wv = t >> 6;
    const int wm = wv & 1, wh = wv >> 1;

    const int a_kp = t >> 3;        // k-pair 0..31 (k = 2*a_kp, 2*a_kp+1)
    const int a_m  = (t & 7) << 2;  // m chunk base

    const int fr = lane & 15, fg = lane >> 4;
    int offA[2], offB[4][2];
    #pragma unroll
    for (int kk = 0; kk < 2; ++kk) offA[kk] = foff(wm * 16 + fr, kk * 4 + fg);
    #pragma unroll
    for (int j = 0; j < 4; ++j)
        #pragma unroll
        for (int kk = 0; kk < 2; ++kk)
            offB[j][kk] = foff(wh * 64 + j * 16 + fr, kk * 4 + fg);

    // two A register sets (static names — rule #20)
    f32x4_t a0x, a0y, a1x, a1y;
    auto LOAD0 = [&](int k0) {
        const float* p = adjb + (size_t)(k0 + a_kp * 2) * 2048 + m0 + a_m;
        a0x = *(const f32x4_t*)(p); a0y = *(const f32x4_t*)(p + 2048);
    };
    auto LOAD1 = [&](int k0) {
        const float* p = adjb + (size_t)(k0 + a_kp * 2) * 2048 + m0 + a_m;
        a1x = *(const f32x4_t*)(p); a1y = *(const f32x4_t*)(p + 2048);
    };
    const int wg = a_kp >> 2, wrd = a_kp & 3;
    auto WRITE0 = [&](int ab) {      // set0 -> Abuf ab
        #pragma unroll
        for (int j = 0; j < 4; ++j) {
            const int m = a_m + j;
            *(unsigned int*)((char*)(&Al[ab][0]) + m * 128
                + ((wg ^ (m & 7)) << 4) + wrd * 4) = cvtpk(a0x[j], a0y[j]);
        }
    };
    auto WRITE1 = [&](int ab) {      // set1 -> Abuf ab
        #pragma unroll
        for (int j = 0; j < 4; ++j) {
            const int m = a_m + j;
            *(unsigned int*)((char*)(&Al[ab][0]) + m * 128
                + ((wg ^ (m & 7)) << 4) + wrd * 4) = cvtpk(a1x[j], a1y[j]);
        }
    };

    f32x4_t acc[4];
    #pragma unroll
    for (int j = 0; j < 4; ++j) acc[j] = f32x4_t{0.f, 0.f, 0.f, 0.f};

    auto COMPUTE = [&](const unsigned short* Ab, const unsigned short* Bb) {
        bf16x8_t af[2];
        #pragma unroll
        for (int kk = 0; kk < 2; ++kk)
            af[kk] = __builtin_bit_cast(bf16x8_t,
                *(const u32x4_t*)((const char*)Ab + offA[kk]));
        #pragma unroll
        for (int j = 0; j < 4; ++j) {
            #pragma unroll
            for (int kk = 0; kk < 2; ++kk) {
                bf16x8_t bfj = __builtin_bit_cast(bf16x8_t,
                    *(const u32x4_t*)((const char*)Bb + offB[j][kk]));
                acc[j] = __builtin_amdgcn_mfma_f32_16x16x32_bf16(af[kk], bfj, acc[j], 0, 0, 0);
            }
        }
    };

    // prologue: out = A(0)2,B(0)4,A(1)2,B(1)4 = 12
    LOAD0(0);          stage_B<4096>(xb, 0,  &Bl[0][0], t);
    LOAD1(64);         stage_B<4096>(xb, 64, &Bl[1][0], t);
    VMCNT(10);         // A(0) done
    WRITE0(0);
    VMCNT(6);          // B(0) done
    LGKM0(); BARRIER();

    int bc = 0;        // s % 3
    for (int s = 0; s < 62; s += 2) {
        // even body: compute(s) uses Al[0], Bl[bc]; loads set0 <- A(s+2)
        {
            int b2 = bc + 2; if (b2 >= 3) b2 -= 3;
            LOAD0((s + 2) * 64);
            stage_B<4096>(xb, (s + 2) * 64, &Bl[b2][0], t);
            COMPUTE(&Al[0][0], &Bl[bc][0]);
            VMCNT(10);                 // A(s+1) done
            WRITE1(1);                 // A(s+1) -> Abuf 1
            VMCNT(6);                  // B(s+1) done
            LGKM0(); BARRIER();
            bc = (bc == 2) ? 0 : bc + 1;
        }
        // odd body: compute(s+1) uses Al[1], Bl[bc]; loads set1 <- A(s+3)
        {
            int b2 = bc + 2; if (b2 >= 3) b2 -= 3;
            LOAD1((s + 3) * 64);
            stage_B<4096>(xb, (s + 3) * 64, &Bl[b2][0], t);
            COMPUTE(&Al[1][0], &Bl[bc][0]);
            VMCNT(10);                 // A(s+2) done
            WRITE0(0);                 // A(s+2) -> Abuf 0
            VMCNT(6);                  // B(s+2) done
            LGKM0(); BARRIER();
            bc = (bc == 2) ? 0 : bc + 1;
        }
    }
    // tail: s = 62 (Abuf 0, Bl[62%3=2]); then s = 63 (Abuf 1, Bl[0])
    COMPUTE(&Al[0][0], &Bl[2][0]);
    VMCNT(4);          // A(63) done (outstanding: B(63)=4)
    WRITE1(1);
    VMCNT(0);
    LGKM0(); BARRIER();
    COMPUTE(&Al[1][0], &Bl[0][0]);

    const int mrow = m0 + wm * 16 + (lane >> 4) * 4;
    #pragma unroll
    for (int j = 0; j < 4; ++j) {
        int col = wh * 64 + j * 16 + fr;
        unsigned int o0 = cvtpk(acc[j][0], acc[j][1]);
        unsigned int o1 = cvtpk(acc[j][2], acc[j][3]);
        unsigned int* dst = (unsigned int*)(latT + (size_t)(b * 128 + col) * 2048 + mrow);
        dst[0] = o0; dst[1] = o1;
    }
}

// ---------------------------------------------------------------------------
// Kernel 3: ret[b][n][h] = sum_m adj[b][n][m] * latT[b][h][m]
// grid 1024 = 8b x 128nt(32n). Same pipeline, NS=32 steps.
// A rows k-contiguous: 2 f32x4 loads -> 4 cvtpk -> one b128 swizzled write.
// ---------------------------------------------------------------------------
__global__ __launch_bounds__(256) void k3_ret(
    const float* __restrict__ adj,
    const unsigned short* __restrict__ latT,
    float* __restrict__ ret)
{
    __shared__ unsigned short Al[2][32 * 64];    // [n][k] bf16
    __shared__ unsigned short Bl[3][128 * 64];   // [h][k] bf16

    const int t   = threadIdx.x;
    const int bid = blockIdx.x;
    const int b   = bid & 7;
    const int n0  = (bid >> 3) << 5;
    const float* adjb = adj + (size_t)b * 4096 * 2048;
    const unsigned short* lb = latT + (size_t)b * 128 * 2048;

    const int lane = t & 63, wv = t >> 6;
    const int wn = wv & 1, wh = wv >> 1;

    const int a_r = t >> 3;         // n-row 0..31
    const int a_c = t & 7;          // k-granule 0..7

    const int fr = lane & 15, fg = lane >> 4;
    int offA[2], offB[4][2];
    #pragma unroll
    for (int kk = 0; kk < 2; ++kk) offA[kk] = foff(wn * 16 + fr, kk * 4 + fg);
    #pragma unroll
    for (int j = 0; j < 4; ++j)
        #pragma unroll
        for (int kk = 0; kk < 2; ++kk)
            offB[j][kk] = foff(wh * 64 + j * 16 + fr, kk * 4 + fg);

    f32x4_t a0x, a0y, a1x, a1y;
    auto LOAD0 = [&](int k0) {
        const float* p = adjb + (size_t)(n0 + a_r) * 2048 + k0 + a_c * 8;
        a0x = *(const f32x4_t*)(p); a0y = *(const f32x4_t*)(p + 4);
    };
    auto LOAD1 = [&](int k0) {
        const float* p = adjb + (size_t)(n0 + a_r) * 2048 + k0 + a_c * 8;
        a1x = *(const f32x4_t*)(p); a1y = *(const f32x4_t*)(p + 4);
    };
    const int awoff = ((a_c ^ (a_r & 7)) << 4);
    auto WRITE0 = [&](int ab) {
        u32x4_t pk;
        pk[0] = cvtpk(a0x[0], a0x[1]); pk[1] = cvtpk(a0x[2], a0x[3]);
        pk[2] = cvtpk(a0y[0], a0y[1]); pk[3] = cvtpk(a0y[2], a0y[3]);
        *(u32x4_t*)((char*)(&Al[ab][0]) + a_r * 128 + awoff) = pk;
    };
    auto WRITE1 = [&](int ab) {
        u32x4_t pk;
        pk[0] = cvtpk(a1x[0], a1x[1]); pk[1] = cvtpk(a1x[2], a1x[3]);
        pk[2] = cvtpk(a1y[0], a1y[1]); pk[3] = cvtpk(a1y[2], a1y[3]);
        *(u32x4_t*)((char*)(&Al[ab][0]) + a_r * 128 + awoff) = pk;
    };

    f32x4_t acc[4];
    #pragma unroll
    for (int j = 0; j < 4; ++j) acc[j] = f32x4_t{0.f, 0.f, 0.f, 0.f};

    auto COMPUTE = [&](const unsigned short* Ab, const unsigned short* Bb) {
        bf16x8_t af[2];
        #pragma unroll
        for (int kk = 0; kk < 2; ++kk)
            af[kk] = __builtin_bit_cast(bf16x8_t,
                *(const u32x4_t*)((const char*)Ab + offA[kk]));
        #pragma unroll
        for (int j = 0; j < 4; ++j) {
            #pragma unroll
            for (int kk = 0; kk < 2; ++kk) {
                bf16x8_t bfj = __builtin_bit_cast(bf16x8_t,
                    *(const u32x4_t*)((const char*)Bb + offB[j][kk]));
                acc[j] = __builtin_amdgcn_mfma_f32_16x16x32_bf16(af[kk], bfj, acc[j], 0, 0, 0);
            }
        }
    };

    LOAD0(0);          stage_B<2048>(lb, 0,  &Bl[0][0], t);
    LOAD1(64);         stage_B<2048>(lb, 64, &Bl[1][0], t);
    VMCNT(10);
    WRITE0(0);
    VMCNT(6);
    LGKM0(); BARRIER();

    int bc = 0;
    for (int s = 0; s < 30; s += 2) {
        {
            int b2 = bc + 2; if (b2 >= 3) b2 -= 3;
            LOAD0((s + 2) * 64);
            stage_B<2048>(lb, (s + 2) * 64, &Bl[b2][0], t);
            COMPUTE(&Al[0][0], &Bl[bc][0]);
            VMCNT(10);
            WRITE1(1);
            VMCNT(6);
            LGKM0(); BARRIER();
            bc = (bc == 2) ? 0 : bc + 1;
        }
        {
            int b2 = bc + 2; if (b2 >= 3) b2 -= 3;
            LOAD1((s + 3) * 64);
            stage_B<2048>(lb, (s + 3) * 64, &Bl[b2][0], t);
            COMPUTE(&Al[1][0], &Bl[bc][0]);
            VMCNT(10);
            WRITE0(0);
            VMCNT(6);
            LGKM0(); BARRIER();
            bc = (bc == 2) ? 0 : bc + 1;
        }
    }
    // tail: s = 30 (Abuf 0, Bl[30%3=0]); s = 31 (Abuf 1, Bl[31%3=1])
    COMPUTE(&Al[0][0], &Bl[0][0]);
    VMCNT(4);
    WRITE1(1);
    VMCNT(0);
    LGKM0(); BARRIER();
    COMPUTE(&Al[1][0], &Bl[1][0]);

    const int nrow = n0 + wn * 16 + (lane >> 4) * 4;
    #pragma unroll
    for (int j = 0; j < 4; ++j) {
        int col = wh * 64 + j * 16 + fr;
        #pragma unroll
        for (int jj = 0; jj < 4; ++jj) {
            ret[((size_t)b * 4096 + nrow + jj) * 128 + col] = acc[j][jj];
        }
    }
}

// ---------------------------------------------------------------------------
extern "C" void kernel_launch(void* const* d_in, const int* in_sizes, int n_in,
                              void* d_out, int out_size, void* d_ws, size_t ws_size,
                              hipStream_t stream) {
    const float* adj    = (const float*)d_in[0];
    const float* embeds = (const float*)d_in[1];
    const int*   ntype  = (const int*)d_in[2];
    const unsigned char* mask8 = (const unsigned char*)d_in[3];
    const float* W      = (const float*)d_in[4];
    const float* bias   = (const float*)d_in[5];
    const float* gamma  = (const float*)d_in[6];
    const float* beta   = (const float*)d_in[7];
    float* ret = (float*)d_out;

    unsigned short* xT   = (unsigned short*)d_ws;                   // 8.39 MB
    unsigned short* latT = xT + (size_t)8 * 128 * 4096;             // 4.19 MB
    // ws needed: 12.6 MB

    hipLaunchKernelGGL(k1_typed_ln, dim3(256), dim3(256), 0, stream,
                       embeds, ntype, mask8, W, bias, gamma, beta, xT);
    hipLaunchKernelGGL(k2_lat, dim3(512), dim3(256), 0, stream, adj, xT, latT);
    hipLaunchKernelGGL(k3_ret, dim3(1024), dim3(256), 0, stream, adj, latT, ret);
}